// Round 1
// baseline (1791.670 us; speedup 1.0000x reference)
//
#include <hip/hip_runtime.h>
#include <math.h>

// Problem constants
#define B_    256
#define NPTS  1024
#define T_    50

// ---------------------------------------------------------------------------
// ws layout (bytes):
//   [0,       786432)   wp   f32 [64][3][256][4]  packed W_hh (round-7 layout)
//   [786432,  1310720)  henc u32 [256][512]       (f32-bit maxpool via atomicMax)
//   [1310720, 1441792)  ow1d f64 [256][64]
//   [1441792, 1474560)  ow2d f64 [64][64]
//   [1474560, 1477632)  ow3d f64 [64][6]
// ---------------------------------------------------------------------------

__global__ __launch_bounds__(256) void prep_kernel(
    const float* __restrict__ whh, const float* __restrict__ ow1,
    const float* __restrict__ ow2, const float* __restrict__ ow3,
    float* __restrict__ wp, unsigned* __restrict__ henc,
    double* __restrict__ ow1d, double* __restrict__ ow2d,
    double* __restrict__ ow3d) {
  int idx = blockIdx.x * 256 + threadIdx.x;   // grid 768*256 = 196608
  if (idx < 196608) {
    int c = idx & 3;
    int r = idx >> 2;            // (k4*3+j)*256 + t
    int t2 = r & 255;
    int q = r >> 8;              // k4*3 + j
    int j = q % 3;
    int k4 = q / 3;
    wp[idx] = whh[(j * 256 + t2) * 256 + (k4 * 4 + c)];
  }
  if (idx < 131072) henc[idx] = 0u;           // bits 0 == +0.0f; relu>=0 valid
  if (idx < 16384) ow1d[idx] = (double)ow1[idx];
  if (idx < 4096)  ow2d[idx] = (double)ow2[idx];
  if (idx < 384)   ow3d[idx] = (double)ow3[idx];
}

// ---------------------------------------------------------------------------
// Encoder (byte-identical math to passing rounds 5-7): block = half sample,
// grid 512. Wave-uniform output slices -> weights via scalar s_loads.
// ---------------------------------------------------------------------------
__global__ __launch_bounds__(1024) void enc_kernel(
    const float* __restrict__ data,
    const float* __restrict__ w1, const float* __restrict__ b1,
    const float* __restrict__ w2, const float* __restrict__ b2,
    const float* __restrict__ w3, const float* __restrict__ b3,
    unsigned* __restrict__ henc) {
  __shared__ float h2t[128][66];
  const int t = threadIdx.x;
  const int b = blockIdx.x >> 1;
  const int half = blockIdx.x & 1;
  const int lane = t & 63;
  const int wv = __builtin_amdgcn_readfirstlane(t >> 6);   // wave id 0..15

  float m[32];
#pragma unroll
  for (int o = 0; o < 32; ++o) m[o] = 0.0f;                // relu via max w/ 0
  const float* __restrict__ w3b = w3 + wv * 32;

#pragma unroll 1
  for (int tile = 0; tile < 8; ++tile) {
    {
      const int ptg = b * NPTS + half * 512 + tile * 64 + lane;
      const float x0 = data[ptg * 3], x1 = data[ptg * 3 + 1], x2 = data[ptg * 3 + 2];
      float a[8];
#pragma unroll
      for (int c = 0; c < 8; ++c) a[c] = b2[wv * 8 + c];   // s_load
#pragma unroll 4
      for (int j = 0; j < 64; ++j) {                       // w1/b1 uniform
        float hj = fmaf(x0, w1[j], fmaf(x1, w1[64 + j], fmaf(x2, w1[128 + j], b1[j])));
        hj = fmaxf(hj, 0.0f);
        const float* __restrict__ w2r = w2 + j * 128 + wv * 8;  // s_load x8
#pragma unroll
        for (int c = 0; c < 8; ++c) a[c] = fmaf(hj, w2r[c], a[c]);
      }
#pragma unroll
      for (int c = 0; c < 8; ++c) h2t[wv * 8 + c][lane] = fmaxf(a[c], 0.0f);
    }
    __syncthreads();

    float acc[32];
#pragma unroll
    for (int o = 0; o < 32; ++o) acc[o] = b3[wv * 32 + o]; // s_load
#pragma unroll 4
    for (int k = 0; k < 128; ++k) {
      const float hk = h2t[k][lane];                       // ds_read_b32
      const float* __restrict__ wr = w3b + k * 512;        // uniform -> s_load
#pragma unroll
      for (int o = 0; o < 32; ++o) acc[o] = fmaf(hk, wr[o], acc[o]);
    }
#pragma unroll
    for (int o = 0; o < 32; ++o) m[o] = fmaxf(m[o], acc[o]);
    __syncthreads();                                       // h2t reuse guard
  }

#pragma unroll
  for (int off = 32; off > 0; off >>= 1) {
#pragma unroll
    for (int o = 0; o < 32; ++o) m[o] = fmaxf(m[o], __shfl_xor(m[o], off, 64));
  }
  if (lane == 0) {
    unsigned* __restrict__ hr = henc + b * 512 + wv * 32;
#pragma unroll
    for (int o = 0; o < 32; ++o) atomicMax(hr + o, __float_as_uint(m[o]));
  }
}

// ---------------------------------------------------------------------------
// Fast f64 exp (Cody-Waite + degree-13 Taylor, exact 1/k! coeffs, branch-
// free, ~1 ulp for |x| < 700). Perturbs vs libm at ~1e-16 rel -> invisible
// at f32 output rounding (f64-perturbation invariance proven rounds 4-7).
// ---------------------------------------------------------------------------
__device__ __forceinline__ double fexp(double x) {
  const double n = rint(x * 1.44269504088896338700e+00);
  const double r = fma(-n, 1.90821492927058770002e-10,
                       fma(-n, 6.93147180369123816490e-01, x));
  double p = 1.0 / 6227020800.0;                 // 1/13!
  p = fma(p, r, 1.0 / 479001600.0);
  p = fma(p, r, 1.0 / 39916800.0);
  p = fma(p, r, 1.0 / 3628800.0);
  p = fma(p, r, 1.0 / 362880.0);
  p = fma(p, r, 1.0 / 40320.0);
  p = fma(p, r, 1.0 / 5040.0);
  p = fma(p, r, 1.0 / 720.0);
  p = fma(p, r, 1.0 / 120.0);
  p = fma(p, r, 1.0 / 24.0);
  p = fma(p, r, 1.0 / 6.0);
  p = fma(p, r, 0.5);
  p = fma(p, r, 1.0);
  p = fma(p, r, 1.0);
  return ldexp(p, (int)n);
}
__device__ __forceinline__ double fsigm(double x) { return 1.0 / (1.0 + fexp(-x)); }
__device__ __forceinline__ double ftanh(double y) {
  const double e = fexp(-2.0 * y);
  return (1.0 - e) / (1.0 + e);
}

// ---------------------------------------------------------------------------
// GRU rollout, f64, grid 128, block = 2 samples x 1024 threads (16 waves).
// Restructure vs round-8 (640 thr, 2 matvec waves/SIMD, VALUBusy 14.6-21%):
// matvec k-split 4 ways -> thread (c = t&255, quarter q = t>>8); q0-q2 own
// 18 k4 each, q3 owns 10 k4 AND absorbs the out_mlp stages in the same
// c1/c2/c3 phase slots (load-balanced). 4 matvec waves/SIMD now hide L2
// wp-load latency and f64 chains that 2 waves could not. Quarter partials
// published to pp[q]; gate threads (t<512: c, sample g) sum bias + 4
// ascending-k quarters (same f64 ordering class as the proven half-split;
// perturbation invisible at f32 output rounding). Gates use fexp/fsigm/
// ftanh as before. out_mlp: c1 L1 4-way k-split (each ow1d weight read
// once), c2 combine+L2 wave-synchronous (wave12=g0, wave13=g1 read only
// own o1_l row after wave_barrier), c3 L3+gia+stores (12 thr).
// ---------------------------------------------------------------------------
__global__ __launch_bounds__(1024) void gru_kernel(
    const float* __restrict__ henc,     // [256][512] (maxpool bits)
    const float* __restrict__ mw1, const float* __restrict__ mb1,
    const float* __restrict__ mw2, const float* __restrict__ mb2,
    const float* __restrict__ mw3, const float* __restrict__ mb3,
    const float* __restrict__ wih, const float* __restrict__ wp,
    const float* __restrict__ bih, const float* __restrict__ bhh,
    const double* __restrict__ ow1d, const float* __restrict__ ob1,
    const double* __restrict__ ow2d, const float* __restrict__ ob2,
    const double* __restrict__ ow3d, const float* __restrict__ ob3,
    float* __restrict__ dout) {
  __shared__ __align__(16) double h_l[512];   // [g][c]
  __shared__ double pp[4][3][2][256];         // [quarter][gate][sample][c]
  __shared__ double g1_l[512];                // phase 0
  __shared__ double g2_l[256];                // phase 0
  __shared__ double o1p[4][2][64];            // [ksplit][g][j] L1 partials
  __shared__ double o1_l[2][64];
  __shared__ double o2_l[2][64];
  __shared__ double gia_l[12];                // [g][c]
  __shared__ double wihd[4608];
  __shared__ double bihd[768];

  const int t = threadIdx.x;
  const int s0 = blockIdx.x << 1;

  for (int i = t; i < 4608; i += 1024) wihd[i] = (double)wih[i];
  for (int i = t; i < 768; i += 1024) bihd[i] = (double)bih[i];

  // ---- phase 0: gru_h init MLP (512->256->128->256), f64 (round-7 math) --
  if (t < 512) {
    const int o = t & 255, g = t >> 8;                    // g wave-uniform
    const float* __restrict__ hrow = henc + ((s0 + g) << 9);   // uniform
    double a = (double)mb1[o];
#pragma unroll 4
    for (int k = 0; k < 512; ++k)
      a = fma((double)hrow[k], (double)mw1[k * 256 + o], a);
    g1_l[(g << 8) + o] = fmax(a, 0.0);
  }
  __syncthreads();
  if (t < 256) {
    const int o = t & 127, g = t >> 7;
    double a = (double)mb2[o];
#pragma unroll 4
    for (int k = 0; k < 256; ++k) a = fma(g1_l[(g << 8) + k], (double)mw2[k * 128 + o], a);
    g2_l[(g << 7) + o] = fmax(a, 0.0);
  }
  __syncthreads();
  if (t < 512) {
    const int o = t & 255, g = t >> 8;
    double a = (double)mb3[o];
#pragma unroll 4
    for (int k = 0; k < 128; ++k) a = fma(g2_l[(g << 7) + k], (double)mw3[k * 256 + o], a);
    h_l[(g << 8) + o] = a;
  }
  if (t < 12) gia_l[t] = 0.0;
  __syncthreads();

  // ---- matvec thread constants ----
  const int c = t & 255;
  const int q = t >> 8;                        // k-quarter 0..3
  const int kb = q * 18;                       // q3 base = 54
  const int e1 = (q < 3) ? 7 : 3;              // c1 k4 count
  const int e2 = (q < 3) ? 14 : 7;             // end of c2 (rel)
  const int eT = (q < 3) ? 18 : 10;            // total k4
  // gate-thread constants (t<512): sample g == q
  const int g = q & 1;
  const double br = (t < 512) ? (double)bhh[c] : 0.0;
  const double bz = (t < 512) ? (double)bhh[256 + c] : 0.0;
  const double bn = (t < 512) ? (double)bhh[512 + c] : 0.0;
  double hreg = (t < 512) ? h_l[(g << 8) + c] : 0.0;
  const int tb = t - 768;                      // out_mlp id (>=0 for q3)

  double ar0, ar1, az0, az1, an0, an1;

#define MV_K4(k4) {                                                          \
    const int wbase = ((k4) * 768 + c) * 4;                                  \
    const float4 wr = *(const float4*)(wp + wbase);                          \
    const float4 wz = *(const float4*)(wp + wbase + 1024);                   \
    const float4 wn = *(const float4*)(wp + wbase + 2048);                   \
    const double2 ha = *(const double2*)(h_l + ((k4) << 2));                 \
    const double2 hb = *(const double2*)(h_l + ((k4) << 2) + 2);             \
    const double2 hc = *(const double2*)(h_l + 256 + ((k4) << 2));           \
    const double2 hd = *(const double2*)(h_l + 256 + ((k4) << 2) + 2);       \
    ar0 = fma(ha.x, (double)wr.x, ar0); ar0 = fma(ha.y, (double)wr.y, ar0);  \
    ar0 = fma(hb.x, (double)wr.z, ar0); ar0 = fma(hb.y, (double)wr.w, ar0);  \
    az0 = fma(ha.x, (double)wz.x, az0); az0 = fma(ha.y, (double)wz.y, az0);  \
    az0 = fma(hb.x, (double)wz.z, az0); az0 = fma(hb.y, (double)wz.w, az0);  \
    an0 = fma(ha.x, (double)wn.x, an0); an0 = fma(ha.y, (double)wn.y, an0);  \
    an0 = fma(hb.x, (double)wn.z, an0); an0 = fma(hb.y, (double)wn.w, an0);  \
    ar1 = fma(hc.x, (double)wr.x, ar1); ar1 = fma(hc.y, (double)wr.y, ar1);  \
    ar1 = fma(hd.x, (double)wr.z, ar1); ar1 = fma(hd.y, (double)wr.w, ar1);  \
    az1 = fma(hc.x, (double)wz.x, az1); az1 = fma(hc.y, (double)wz.y, az1);  \
    az1 = fma(hd.x, (double)wz.z, az1); az1 = fma(hd.y, (double)wz.w, az1);  \
    an1 = fma(hc.x, (double)wn.x, an1); an1 = fma(hc.y, (double)wn.y, an1);  \
    an1 = fma(hd.x, (double)wn.z, an1); an1 = fma(hd.y, (double)wn.w, an1);  \
  }
#define MV_PUBLISH() {                                                       \
    pp[q][0][0][c] = ar0; pp[q][0][1][c] = ar1;                              \
    pp[q][1][0][c] = az0; pp[q][1][1][c] = az1;                              \
    pp[q][2][0][c] = an0; pp[q][2][1][c] = an1;                              \
  }

  // ---- prologue: all quarter partials of comb(h0) ----
  ar0 = 0.0; ar1 = 0.0; az0 = 0.0; az1 = 0.0; an0 = 0.0; an1 = 0.0;
#pragma unroll 2
  for (int k4 = kb; k4 < kb + eT; ++k4) MV_K4(k4);
  MV_PUBLISH();
  __syncthreads();

  for (int step = 0; step < T_; ++step) {
    // ---- gates for sample g (t<512): comb = bias + 4 ascending quarters --
    if (t < 512) {
      const double cr = br + pp[0][0][g][c] + pp[1][0][g][c]
                           + pp[2][0][g][c] + pp[3][0][g][c];
      const double cz = bz + pp[0][1][g][c] + pp[1][1][g][c]
                           + pp[2][1][g][c] + pp[3][1][g][c];
      const double cn = bn + pp[0][2][g][c] + pp[1][2][g][c]
                           + pp[2][2][g][c] + pp[3][2][g][c];
      double gr = bihd[c], gz = bihd[256 + c], gn = bihd[512 + c];
#pragma unroll
      for (int a = 0; a < 6; ++a) {
        const double xa = gia_l[g * 6 + a];
        gr = fma(wihd[c * 6 + a], xa, gr);
        gz = fma(wihd[(256 + c) * 6 + a], xa, gz);
        gn = fma(wihd[(512 + c) * 6 + a], xa, gn);
      }
      const double rv = fsigm(cr + gr);
      const double zv = fsigm(cz + gz);
      const double nv = ftanh(fma(rv, cn, gn));
      hreg = fma(zv, hreg - nv, nv);
      h_l[(g << 8) + c] = hreg;
    }
    ar0 = 0.0; ar1 = 0.0; az0 = 0.0; az1 = 0.0; an0 = 0.0; an1 = 0.0;
    __syncthreads();                    // h published

    // ---- c1: matvec chunk 1 || out_mlp L1 (4-way k-split, 256 thr) ----
#pragma unroll 2
    for (int k4 = kb; k4 < kb + e1; ++k4) MV_K4(k4);
    if (tb >= 0) {
      const int kp = tb >> 6, j = tb & 63;
      double a0 = (kp == 0) ? (double)ob1[j] : 0.0;
      double a1 = a0;
      const int k0 = kp << 6;
#pragma unroll 4
      for (int k = k0; k < k0 + 64; ++k) {
        const double wv = ow1d[k * 64 + j];               // coalesced, once
        a0 = fma(h_l[k], wv, a0);                         // h broadcast
        a1 = fma(h_l[256 + k], wv, a1);
      }
      o1p[kp][0][j] = a0; o1p[kp][1][j] = a1;
    }
    __syncthreads();

    // ---- c2: matvec chunk 2 || combine o1 + L2 (wave-synchronous) ----
#pragma unroll 2
    for (int k4 = kb + e1; k4 < kb + e2; ++k4) MV_K4(k4);
    if (tb >= 0 && tb < 128) {
      const int gg = tb >> 6, j = tb & 63;                // wave12=g0, wave13=g1
      o1_l[gg][j] = fmax(((o1p[0][gg][j] + o1p[1][gg][j])
                          + o1p[2][gg][j]) + o1p[3][gg][j], 0.0);
      __builtin_amdgcn_wave_barrier();                    // own-wave LDS only
      double b0 = (double)ob2[j];
#pragma unroll 4
      for (int k = 0; k < 64; ++k)
        b0 = fma(o1_l[gg][k], ow2d[k * 64 + j], b0);
      o2_l[gg][j] = fmax(b0, 0.0);
    }
    __syncthreads();

    // ---- c3: matvec chunk 3 + publish || L3 + gia + stores ----
#pragma unroll 2
    for (int k4 = kb + e2; k4 < kb + eT; ++k4) MV_K4(k4);
    MV_PUBLISH();
    if (tb >= 0 && tb < 12) {
      const int gg = tb / 6, cc = tb - gg * 6;
      double a = (double)ob3[cc];
#pragma unroll 4
      for (int k = 0; k < 64; ++k) a = fma(o2_l[gg][k], ow3d[k * 6 + cc], a);
      const double gi_new = gia_l[gg * 6 + cc] + a;
      gia_l[gg * 6 + cc] = gi_new;
      const int s = s0 + gg;
      dout[s * 300 + step * 6 + cc] = (float)a;              // dws
      dout[76800 + s * 300 + step * 6 + cc] = (float)gi_new; // ws
    }
    __syncthreads();                    // pp + gia ready for next gates
  }
#undef MV_K4
#undef MV_PUBLISH
}

extern "C" void kernel_launch(void* const* d_in, const int* in_sizes, int n_in,
                              void* d_out, int out_size, void* d_ws, size_t ws_size,
                              hipStream_t stream) {
  const float* data = (const float*)d_in[0];
  // d_in[1] = horizon (always 50)
  const float* ew1 = (const float*)d_in[2];
  const float* eb1 = (const float*)d_in[3];
  const float* ew2 = (const float*)d_in[4];
  const float* eb2 = (const float*)d_in[5];
  const float* ew3 = (const float*)d_in[6];
  const float* eb3 = (const float*)d_in[7];
  const float* mw1 = (const float*)d_in[8];
  const float* mb1 = (const float*)d_in[9];
  const float* mw2 = (const float*)d_in[10];
  const float* mb2 = (const float*)d_in[11];
  const float* mw3 = (const float*)d_in[12];
  const float* mb3 = (const float*)d_in[13];
  const float* wih = (const float*)d_in[14];
  const float* whh = (const float*)d_in[15];
  const float* bih = (const float*)d_in[16];
  const float* bhh = (const float*)d_in[17];
  const float* ow1 = (const float*)d_in[18];
  const float* ob1 = (const float*)d_in[19];
  const float* ow2 = (const float*)d_in[20];
  const float* ob2 = (const float*)d_in[21];
  const float* ow3 = (const float*)d_in[22];
  const float* ob3 = (const float*)d_in[23];
  float* out = (float*)d_out;

  char* ws = (char*)d_ws;
  float*    wp   = (float*)(ws);                 // 786432 B
  unsigned* henc = (unsigned*)(ws + 786432);     // 524288 B
  double*   ow1d = (double*)(ws + 1310720);      // 131072 B
  double*   ow2d = (double*)(ws + 1441792);      // 32768 B
  double*   ow3d = (double*)(ws + 1474560);      // 3072 B -> end 1477632

  prep_kernel<<<768, 256, 0, stream>>>(whh, ow1, ow2, ow3, wp, henc,
                                       ow1d, ow2d, ow3d);
  enc_kernel<<<512, 1024, 0, stream>>>(data, ew1, eb1, ew2, eb2, ew3, eb3, henc);
  gru_kernel<<<128, 1024, 0, stream>>>((const float*)henc,
                                       mw1, mb1, mw2, mb2, mw3, mb3,
                                       wih, wp, bih, bhh,
                                       ow1d, ob1, ow2d, ob2, ow3d, ob3,
                                       out);
}